// Round 2
// 954.059 us; speedup vs baseline: 1.2540x; 1.2540x over previous
//
#include <hip/hip_runtime.h>
#include <hip/hip_bf16.h>
#include <math.h>

#define NN 40000
#define EE 250000
#define HH 4
#define DD 64
#define HDIM 256

typedef __attribute__((ext_vector_type(8))) short short8;
typedef __attribute__((ext_vector_type(4))) float floatx4;
typedef __attribute__((ext_vector_type(4))) unsigned short ushortx4;

#define ASYNC16(G, L) __builtin_amdgcn_global_load_lds( \
    (const __attribute__((address_space(1))) void*)(G), \
    (__attribute__((address_space(3))) void*)(L), 16, 0, 0)

__device__ __forceinline__ float b2f(unsigned short u) {
    return __uint_as_float((unsigned)u << 16);
}
__device__ __forceinline__ unsigned short f2bu(float x) {
    __hip_bfloat16 h = __float2bfloat16(x);
    return *(unsigned short*)&h;
}

// ---------------- CSR build ----------------

__global__ void zero_kernel(int* p, int n) {
    int i = blockIdx.x * blockDim.x + threadIdx.x;
    if (i < n) p[i] = 0;
}

// grid.y = etype
__global__ void count3_kernel(const int* __restrict__ d0, const int* __restrict__ d1,
                              const int* __restrict__ d2, int* __restrict__ deg_all, int n) {
    int i = blockIdx.x * blockDim.x + threadIdx.x;
    int t = blockIdx.y;
    const int* dst = t == 0 ? d0 : (t == 1 ? d1 : d2);
    if (i < n) atomicAdd(&deg_all[t * NN + dst[i]], 1);
}

// register-blocked scan: 1024 threads x 40 elems, wave-scan + cross-wave scan.
#define SCAN_PER 40
__global__ __launch_bounds__(1024) void scan3_kernel(const int* __restrict__ deg_all,
                                                     int* __restrict__ rowptr_all, int n) {
    const int* deg = deg_all + blockIdx.x * NN;
    int* rowptr = rowptr_all + blockIdx.x * (NN + 1);
    int tid = threadIdx.x;
    int lane = tid & 63, wv = tid >> 6;
    __shared__ int wsum[16];

    int beg = tid * SCAN_PER;
    int vals[SCAN_PER];
    int loc = 0;
#pragma unroll
    for (int j = 0; j < SCAN_PER; j++) {
        int i = beg + j;
        int v = (i < n) ? deg[i] : 0;
        vals[j] = v;
        loc += v;
    }
    // inclusive wave scan of loc
    int sc = loc;
#pragma unroll
    for (int off = 1; off < 64; off <<= 1) {
        int t2 = __shfl_up(sc, off);
        if (lane >= off) sc += t2;
    }
    if (lane == 63) wsum[wv] = sc;
    __syncthreads();
    if (wv == 0) {
        int w = (lane < 16) ? wsum[lane] : 0;
#pragma unroll
        for (int off = 1; off < 16; off <<= 1) {
            int t2 = __shfl_up(w, off);
            if (lane >= off) w += t2;
        }
        if (lane < 16) wsum[lane] = w;  // inclusive over waves
    }
    __syncthreads();
    int base = (wv > 0 ? wsum[wv - 1] : 0) + (sc - loc);  // exclusive prefix for this thread
    int run = base;
#pragma unroll
    for (int j = 0; j < SCAN_PER; j++) {
        int i = beg + j;
        run += vals[j];
        if (i < n) rowptr[i + 1] = run;
    }
    if (tid == 0) rowptr[0] = 0;
}

__global__ void scatter3_kernel(const int* __restrict__ s0, const int* __restrict__ s1,
                                const int* __restrict__ s2, const int* __restrict__ d0,
                                const int* __restrict__ d1, const int* __restrict__ d2,
                                const int* __restrict__ rowptr_all, int* __restrict__ cur_all,
                                int* __restrict__ colsrc_all, int* __restrict__ coldst_all, int n) {
    int i = blockIdx.x * blockDim.x + threadIdx.x;
    int t = blockIdx.y;
    const int* src = t == 0 ? s0 : (t == 1 ? s1 : s2);
    const int* dst = t == 0 ? d0 : (t == 1 ? d1 : d2);
    if (i < n) {
        int d = dst[i];
        int p = rowptr_all[t * (NN + 1) + d] + atomicAdd(&cur_all[t * NN + d], 1);
        colsrc_all[t * EE + p] = src[i];
        coldst_all[t * EE + p] = d;
    }
}

// ---------------- conversions / weight packing ----------------

// n4 = count of float4 groups
__global__ void f2b_kernel(const float* __restrict__ in, __hip_bfloat16* __restrict__ o, int n4) {
    int i = blockIdx.x * blockDim.x + threadIdx.x;
    if (i < n4) {
        floatx4 v = *(const floatx4*)(in + (size_t)i * 4);
        ushortx4 r;
        r.x = f2bu(v.x); r.y = f2bu(v.y); r.z = f2bu(v.z); r.w = f2bu(v.w);
        *(ushortx4*)((unsigned short*)o + (size_t)i * 4) = r;
    }
}

// Output-indexed transpose: Wt[n][k] = bf16(W[k][n]); W is K x Nc row-major, K = 1<<kshift.
// Coalesced bf16 writes; scattered f32 reads are L2-resident (W <= 1 MB).
__global__ void transb_kernel(const float* __restrict__ W, __hip_bfloat16* __restrict__ Wt,
                              int kshift, int Nc, int total) {
    int i = blockIdx.x * blockDim.x + threadIdx.x;
    if (i < total) {
        int K = 1 << kshift;
        int n2 = i >> kshift, k = i & (K - 1);
        Wt[i] = __float2bfloat16(W[(size_t)k * Nc + n2]);
    }
}

// ---------------- bf16 MFMA GEMM ----------------
// C[M,N] = A[M,K] @ Bt[N,K]^T (+bias). Grid: x = n-tile (fastest, shares A panel), y = m-tile.

template<bool STORE_BF16>
__global__ __launch_bounds__(256) void gemm_mfma(const __hip_bfloat16* __restrict__ A,
                                                 const __hip_bfloat16* __restrict__ Bt,
                                                 const float* __restrict__ bias,
                                                 float* __restrict__ Cf,
                                                 __hip_bfloat16* __restrict__ Cb,
                                                 int M, int N, int K) {
    __shared__ short As[4096];   // 128 rows x 32 k (bf16), swizzled 16B chunks
    __shared__ short Bs[4096];
    int t = threadIdx.x;
    int lane = t & 63;
    int w = t >> 6;
    int m0 = blockIdx.y * 128;
    int n0 = blockIdx.x * 128;
    int wm = (w >> 1) * 64, wn = (w & 1) * 64;

    int c0 = t, c1 = t + 256;
    int row0 = c0 >> 2, row1 = c1 >> 2;
    int kg0 = (c0 & 3) ^ ((row0 >> 1) & 3);
    int kg1 = (c1 & 3) ^ ((row1 >> 1) & 3);
    int am0 = m0 + row0; if (am0 > M - 1) am0 = M - 1;
    int am1 = m0 + row1; if (am1 > M - 1) am1 = M - 1;
    const __hip_bfloat16* Ag0 = A + (size_t)am0 * K + kg0 * 8;
    const __hip_bfloat16* Ag1 = A + (size_t)am1 * K + kg1 * 8;
    const __hip_bfloat16* Bg0 = Bt + (size_t)(n0 + row0) * K + kg0 * 8;
    const __hip_bfloat16* Bg1 = Bt + (size_t)(n0 + row1) * K + kg1 * 8;
    short* lA0 = &As[(t & 192) * 8];
    short* lA1 = &As[(256 + (t & 192)) * 8];
    short* lB0 = &Bs[(t & 192) * 8];
    short* lB1 = &Bs[(256 + (t & 192)) * 8];

    floatx4 acc[4][4];
#pragma unroll
    for (int i = 0; i < 4; i++)
#pragma unroll
        for (int j = 0; j < 4; j++) acc[i][j] = (floatx4){0.f, 0.f, 0.f, 0.f};

    int quad = lane >> 4;
    int lm = lane & 15;

    for (int k0 = 0; k0 < K; k0 += 32) {
        ASYNC16(Ag0 + k0, lA0);
        ASYNC16(Ag1 + k0, lA1);
        ASYNC16(Bg0 + k0, lB0);
        ASYNC16(Bg1 + k0, lB1);
        __syncthreads();

        short8 af[4], bf[4];
#pragma unroll
        for (int i = 0; i < 4; i++) {
            int rm = wm + i * 16 + lm;
            af[i] = *(const short8*)&As[(rm * 4 + (quad ^ ((rm >> 1) & 3))) * 8];
            int rn = wn + i * 16 + lm;
            bf[i] = *(const short8*)&Bs[(rn * 4 + (quad ^ ((rn >> 1) & 3))) * 8];
        }
#pragma unroll
        for (int i = 0; i < 4; i++)
#pragma unroll
            for (int j = 0; j < 4; j++)
                acc[i][j] = __builtin_amdgcn_mfma_f32_16x16x32_bf16(af[i], bf[j], acc[i][j], 0, 0, 0);
        __syncthreads();
    }

    int lr = (lane >> 4) * 4;
#pragma unroll
    for (int i = 0; i < 4; i++) {
#pragma unroll
        for (int j = 0; j < 4; j++) {
            int col = n0 + wn + j * 16 + lm;
            float bv = bias ? bias[col] : 0.0f;
#pragma unroll
            for (int r = 0; r < 4; r++) {
                int row = m0 + wm + i * 16 + lr + r;
                if (row < M) {
                    float v = acc[i][j][r] + bv;
                    if (STORE_BF16) Cb[(size_t)row * N + col] = __float2bfloat16(v);
                    else            Cf[(size_t)row * N + col] = v;
                }
            }
        }
    }
}

// ---------------- el/er for all 3 etypes ----------------

__global__ __launch_bounds__(256) void elr3_kernel(const __hip_bfloat16* __restrict__ f,
                                                   const float* __restrict__ al0, const float* __restrict__ al1,
                                                   const float* __restrict__ al2, const float* __restrict__ ar0,
                                                   const float* __restrict__ ar1, const float* __restrict__ ar2,
                                                   float* __restrict__ el, float* __restrict__ er) {
    int n = blockIdx.x;
    int h = threadIdx.x >> 6;
    int d = threadIdx.x & 63;
#pragma unroll
    for (int t = 0; t < 3; t++) {
        const float* al = t == 0 ? al0 : (t == 1 ? al1 : al2);
        const float* ar = t == 0 ? ar0 : (t == 1 ? ar1 : ar2);
        float v = __bfloat162float(f[(size_t)n * 768 + t * 256 + h * DD + d]);
        float vl = v * al[h * DD + d];
        float vr = v * ar[h * DD + d];
#pragma unroll
        for (int off = 32; off; off >>= 1) {
            vl += __shfl_down(vl, off);
            vr += __shfl_down(vr, off);
        }
        if (d == 0) {
            el[n * 12 + t * 4 + h] = vl;
            er[n * 12 + t * 4 + h] = vr;
        }
    }
}

// ---------------- edge-parallel attention weights ----------------
// ex = exp(leaky(el[src]+er[dst], 0.2)). No max-subtraction: softmax is invariant to it
// and logits are O(1) here (no overflow). attn layout: [t*EE + p][h] floats.

__global__ __launch_bounds__(256) void attn3_kernel(const int* __restrict__ colsrc_all,
                                                    const int* __restrict__ coldst_all,
                                                    const float* __restrict__ el,
                                                    const float* __restrict__ er,
                                                    float* __restrict__ attn_all) {
    int p = blockIdx.x * blockDim.x + threadIdx.x;
    int t = blockIdx.y;
    if (p >= EE) return;
    int src = colsrc_all[t * EE + p];
    int dst = coldst_all[t * EE + p];
    floatx4 l = *(const floatx4*)(el + (size_t)src * 12 + t * 4);
    floatx4 r = *(const floatx4*)(er + (size_t)dst * 12 + t * 4);
    floatx4 o;
#pragma unroll
    for (int j = 0; j < 4; j++) {
        float e = l[j] + r[j];
        e = (e > 0.f) ? e : 0.2f * e;
        o[j] = __expf(e);
    }
    *(floatx4*)(attn_all + ((size_t)t * EE + p) * 4) = o;
}

// ---------------- shuffle-free aggregation ----------------
// One wave per node. Lane owns channels [lane*4, lane*4+3] (head = lane>>4).
// Per edge: uniform colsrc load + per-lane attn load + one ushort4 gather + 4 fma.
// s (softmax denom) accumulates uniformly within each 16-lane head group.

__global__ __launch_bounds__(256) void aggregate3v2_kernel(const int* __restrict__ rowptr_all,
                                                           const int* __restrict__ colsrc_all,
                                                           const float* __restrict__ attn_all,
                                                           const __hip_bfloat16* __restrict__ f,
                                                           const float* __restrict__ b0,
                                                           const float* __restrict__ b1,
                                                           const float* __restrict__ b2,
                                                           float slope,
                                                           __hip_bfloat16* __restrict__ outb) {
    int wid = threadIdx.x >> 6;
    int lane = threadIdx.x & 63;
    int n = blockIdx.x * 4 + wid;
    int hh = lane >> 4;
    const unsigned short* fbase = (const unsigned short*)f;

    float t0 = 0.f, t1 = 0.f, t2 = 0.f, t3 = 0.f;
#pragma unroll
    for (int t = 0; t < 3; t++) {
        const int* rowptr = rowptr_all + t * (NN + 1);
        const int* colsrc = colsrc_all + t * EE;
        const float* attn = attn_all + (size_t)t * EE * 4;
        const unsigned short* fb = fbase + t * 256 + lane * 4;
        int beg = rowptr[n], end = rowptr[n + 1];
        float s = 0.f, a0 = 0.f, a1 = 0.f, a2 = 0.f, a3 = 0.f;
        int p = beg;
        for (; p + 4 <= end; p += 4) {
            int i0 = colsrc[p], i1 = colsrc[p + 1], i2 = colsrc[p + 2], i3 = colsrc[p + 3];
            float e0 = attn[p * 4 + hh];
            float e1 = attn[p * 4 + 4 + hh];
            float e2 = attn[p * 4 + 8 + hh];
            float e3 = attn[p * 4 + 12 + hh];
            ushortx4 v0 = *(const ushortx4*)(fb + (size_t)i0 * 768);
            ushortx4 v1 = *(const ushortx4*)(fb + (size_t)i1 * 768);
            ushortx4 v2 = *(const ushortx4*)(fb + (size_t)i2 * 768);
            ushortx4 v3 = *(const ushortx4*)(fb + (size_t)i3 * 768);
            s += (e0 + e1) + (e2 + e3);
            a0 = fmaf(e0, b2f(v0.x), a0); a1 = fmaf(e0, b2f(v0.y), a1);
            a2 = fmaf(e0, b2f(v0.z), a2); a3 = fmaf(e0, b2f(v0.w), a3);
            a0 = fmaf(e1, b2f(v1.x), a0); a1 = fmaf(e1, b2f(v1.y), a1);
            a2 = fmaf(e1, b2f(v1.z), a2); a3 = fmaf(e1, b2f(v1.w), a3);
            a0 = fmaf(e2, b2f(v2.x), a0); a1 = fmaf(e2, b2f(v2.y), a1);
            a2 = fmaf(e2, b2f(v2.z), a2); a3 = fmaf(e2, b2f(v2.w), a3);
            a0 = fmaf(e3, b2f(v3.x), a0); a1 = fmaf(e3, b2f(v3.y), a1);
            a2 = fmaf(e3, b2f(v3.z), a2); a3 = fmaf(e3, b2f(v3.w), a3);
        }
        for (; p < end; p++) {
            int i0 = colsrc[p];
            float e0 = attn[p * 4 + hh];
            ushortx4 v0 = *(const ushortx4*)(fb + (size_t)i0 * 768);
            s += e0;
            a0 = fmaf(e0, b2f(v0.x), a0); a1 = fmaf(e0, b2f(v0.y), a1);
            a2 = fmaf(e0, b2f(v0.z), a2); a3 = fmaf(e0, b2f(v0.w), a3);
        }
        const float* bias = t == 0 ? b0 : (t == 1 ? b1 : b2);
        floatx4 bv = *(const floatx4*)(bias + lane * 4);
        if (s > 0.f) {
            float inv = 1.0f / s;
            t0 += a0 * inv; t1 += a1 * inv; t2 += a2 * inv; t3 += a3 * inv;
        }
        t0 += bv.x; t1 += bv.y; t2 += bv.z; t3 += bv.w;
    }
    t0 = (t0 >= 0.f) ? t0 : slope * t0;
    t1 = (t1 >= 0.f) ? t1 : slope * t1;
    t2 = (t2 >= 0.f) ? t2 : slope * t2;
    t3 = (t3 >= 0.f) ? t3 : slope * t3;
    ushortx4 o;
    o.x = f2bu(t0); o.y = f2bu(t1); o.z = f2bu(t2); o.w = f2bu(t3);
    *(ushortx4*)((unsigned short*)outb + (size_t)n * HDIM + lane * 4) = o;
}

// ---------------- launch ----------------

extern "C" void kernel_launch(void* const* d_in, const int* in_sizes, int n_in,
                              void* d_out, int out_size, void* d_ws, size_t ws_size,
                              hipStream_t stream) {
    const float* x = (const float*)d_in[0];
    const int* src[3] = {(const int*)d_in[1], (const int*)d_in[3], (const int*)d_in[5]};
    const int* dst[3] = {(const int*)d_in[2], (const int*)d_in[4], (const int*)d_in[6]};
    const float *W[2][3], *AL[2][3], *AR[2][3], *BB[2][3];
    int idx = 7;
    for (int l = 0; l < 2; l++)
        for (int t = 0; t < 3; t++) {
            W[l][t]  = (const float*)d_in[idx++];
            AL[l][t] = (const float*)d_in[idx++];
            AR[l][t] = (const float*)d_in[idx++];
            BB[l][t] = (const float*)d_in[idx++];
        }
    const float* Wout = (const float*)d_in[31];
    const float* bout = (const float*)d_in[32];
    float* out = (float*)d_out;

    // ---- workspace carve ----
    char* p = (char*)d_ws;
    __hip_bfloat16* f_all = (__hip_bfloat16*)p; p += (size_t)NN * 768 * 2;   // 61.44 MB
    char* regionA = p;                          p += (size_t)NN * 1024 * 2;  // 81.92 MB (xb, then hb+attn)
    float* el_all = (float*)p;                  p += (size_t)NN * 12 * 4;
    float* er_all = (float*)p;                  p += (size_t)NN * 12 * 4;
    __hip_bfloat16* Wt0 = (__hip_bfloat16*)p;   p += (size_t)768 * 1024 * 2;
    __hip_bfloat16* Wt1 = (__hip_bfloat16*)p;   p += (size_t)768 * 256 * 2;
    __hip_bfloat16* Wto = (__hip_bfloat16*)p;   p += (size_t)1024 * 256 * 2;
    int* rowptr_all = (int*)p;                  p += (size_t)3 * (NN + 1) * 4;
    int* colsrc_all = (int*)p;                  p += (size_t)3 * EE * 4;
    int* coldst_all = (int*)p;                  p += (size_t)3 * EE * 4;
    int* cursor_all = (int*)p;                  p += (size_t)3 * NN * 4;
    // regionA lifetimes:
    //   xb (layer-k GEMM input) dead once GEMM reads it;
    //   hb = regionA[0 .. 20.48 MB);  attn = regionA[32 MB .. 44 MB) — written after the
    //   GEMM consumed xb, read only by the following aggregate. No overlap with hb.
    __hip_bfloat16* xb = (__hip_bfloat16*)regionA;
    __hip_bfloat16* hb = (__hip_bfloat16*)regionA;
    float* attn_all = (float*)(regionA + (size_t)32 * 1024 * 1024);

    // ---- CSR build ----
    zero_kernel<<<(3 * NN + 255) / 256, 256, 0, stream>>>(cursor_all, 3 * NN);
    count3_kernel<<<dim3((EE + 255) / 256, 3), 256, 0, stream>>>(dst[0], dst[1], dst[2], cursor_all, EE);
    scan3_kernel<<<3, 1024, 0, stream>>>(cursor_all, rowptr_all, NN);
    zero_kernel<<<(3 * NN + 255) / 256, 256, 0, stream>>>(cursor_all, 3 * NN);
    scatter3_kernel<<<dim3((EE + 255) / 256, 3), 256, 0, stream>>>(src[0], src[1], src[2],
                                                                   dst[0], dst[1], dst[2],
                                                                   rowptr_all, cursor_all,
                                                                   colsrc_all, coldst_all, EE);

    // ---- pack inputs/weights to bf16 ----
    f2b_kernel<<<(NN * 1024 / 4 + 255) / 256, 256, 0, stream>>>(x, xb, NN * 1024 / 4);
    for (int t = 0; t < 3; t++) {
        transb_kernel<<<(1024 * 256 + 255) / 256, 256, 0, stream>>>(W[0][t], Wt0 + (size_t)t * 256 * 1024, 10, 256, 256 * 1024);
        transb_kernel<<<(256 * 256 + 255) / 256, 256, 0, stream>>>(W[1][t], Wt1 + (size_t)t * 256 * 256, 8, 256, 256 * 256);
    }
    transb_kernel<<<(256 * 1024 + 255) / 256, 256, 0, stream>>>(Wout, Wto, 8, 1024, 1024 * 256);

    // ---- layer 0 ----
    gemm_mfma<true><<<dim3(6, 313), 256, 0, stream>>>(xb, Wt0, nullptr, nullptr, f_all, NN, 768, 1024);
    elr3_kernel<<<NN, 256, 0, stream>>>(f_all, AL[0][0], AL[0][1], AL[0][2],
                                        AR[0][0], AR[0][1], AR[0][2], el_all, er_all);
    attn3_kernel<<<dim3((EE + 255) / 256, 3), 256, 0, stream>>>(colsrc_all, coldst_all, el_all, er_all, attn_all);
    aggregate3v2_kernel<<<NN / 4, 256, 0, stream>>>(rowptr_all, colsrc_all, attn_all, f_all,
                                                    BB[0][0], BB[0][1], BB[0][2], 0.01f, hb);

    // ---- layer 1 ----
    gemm_mfma<true><<<dim3(6, 313), 256, 0, stream>>>(hb, Wt1, nullptr, nullptr, f_all, NN, 768, 256);
    elr3_kernel<<<NN, 256, 0, stream>>>(f_all, AL[1][0], AL[1][1], AL[1][2],
                                        AR[1][0], AR[1][1], AR[1][2], el_all, er_all);
    attn3_kernel<<<dim3((EE + 255) / 256, 3), 256, 0, stream>>>(colsrc_all, coldst_all, el_all, er_all, attn_all);
    aggregate3v2_kernel<<<NN / 4, 256, 0, stream>>>(rowptr_all, colsrc_all, attn_all, f_all,
                                                    BB[1][0], BB[1][1], BB[1][2], 1.0f, hb);

    // ---- output projection ----
    gemm_mfma<false><<<dim3(8, 313), 256, 0, stream>>>(hb, Wto, bout, out, nullptr, NN, 1024, 256);
}

// Round 3
// 932.430 us; speedup vs baseline: 1.2831x; 1.0232x over previous
//
#include <hip/hip_runtime.h>
#include <hip/hip_bf16.h>
#include <math.h>

#define NN 40000
#define EE 250000
#define HH 4
#define DD 64
#define HDIM 256

typedef __attribute__((ext_vector_type(8))) short short8;
typedef __attribute__((ext_vector_type(4))) float floatx4;
typedef __attribute__((ext_vector_type(4))) unsigned short ushortx4;

#define ASYNC16(G, L) __builtin_amdgcn_global_load_lds( \
    (const __attribute__((address_space(1))) void*)(G), \
    (__attribute__((address_space(3))) void*)(L), 16, 0, 0)

__device__ __forceinline__ float b2f(unsigned short u) {
    return __uint_as_float((unsigned)u << 16);
}
__device__ __forceinline__ unsigned short f2bu(float x) {
    __hip_bfloat16 h = __float2bfloat16(x);
    return *(unsigned short*)&h;
}

// ---------------- CSR build ----------------

__global__ void zero_kernel(int* p, int n) {
    int i = blockIdx.x * blockDim.x + threadIdx.x;
    if (i < n) p[i] = 0;
}

// grid.y = etype
__global__ void count3_kernel(const int* __restrict__ d0, const int* __restrict__ d1,
                              const int* __restrict__ d2, int* __restrict__ deg_all, int n) {
    int i = blockIdx.x * blockDim.x + threadIdx.x;
    int t = blockIdx.y;
    const int* dst = t == 0 ? d0 : (t == 1 ? d1 : d2);
    if (i < n) atomicAdd(&deg_all[t * NN + dst[i]], 1);
}

// register-blocked scan: 1024 threads x 40 elems, wave-scan + cross-wave scan.
#define SCAN_PER 40
__global__ __launch_bounds__(1024) void scan3_kernel(const int* __restrict__ deg_all,
                                                     int* __restrict__ rowptr_all, int n) {
    const int* deg = deg_all + blockIdx.x * NN;
    int* rowptr = rowptr_all + blockIdx.x * (NN + 1);
    int tid = threadIdx.x;
    int lane = tid & 63, wv = tid >> 6;
    __shared__ int wsum[16];

    int beg = tid * SCAN_PER;
    int vals[SCAN_PER];
    int loc = 0;
#pragma unroll
    for (int j = 0; j < SCAN_PER; j++) {
        int i = beg + j;
        int v = (i < n) ? deg[i] : 0;
        vals[j] = v;
        loc += v;
    }
    // inclusive wave scan of loc
    int sc = loc;
#pragma unroll
    for (int off = 1; off < 64; off <<= 1) {
        int t2 = __shfl_up(sc, off);
        if (lane >= off) sc += t2;
    }
    if (lane == 63) wsum[wv] = sc;
    __syncthreads();
    if (wv == 0) {
        int w = (lane < 16) ? wsum[lane] : 0;
#pragma unroll
        for (int off = 1; off < 16; off <<= 1) {
            int t2 = __shfl_up(w, off);
            if (lane >= off) w += t2;
        }
        if (lane < 16) wsum[lane] = w;  // inclusive over waves
    }
    __syncthreads();
    int base = (wv > 0 ? wsum[wv - 1] : 0) + (sc - loc);  // exclusive prefix for this thread
    int run = base;
#pragma unroll
    for (int j = 0; j < SCAN_PER; j++) {
        int i = beg + j;
        run += vals[j];
        if (i < n) rowptr[i + 1] = run;
    }
    if (tid == 0) rowptr[0] = 0;
}

__global__ void scatter3_kernel(const int* __restrict__ s0, const int* __restrict__ s1,
                                const int* __restrict__ s2, const int* __restrict__ d0,
                                const int* __restrict__ d1, const int* __restrict__ d2,
                                const int* __restrict__ rowptr_all, int* __restrict__ cur_all,
                                int* __restrict__ colsrc_all, int* __restrict__ coldst_all, int n) {
    int i = blockIdx.x * blockDim.x + threadIdx.x;
    int t = blockIdx.y;
    const int* src = t == 0 ? s0 : (t == 1 ? s1 : s2);
    const int* dst = t == 0 ? d0 : (t == 1 ? d1 : d2);
    if (i < n) {
        int d = dst[i];
        int p = rowptr_all[t * (NN + 1) + d] + atomicAdd(&cur_all[t * NN + d], 1);
        colsrc_all[t * EE + p] = src[i];
        coldst_all[t * EE + p] = d;
    }
}

// ---------------- conversions / weight packing ----------------

// n4 = count of float4 groups
__global__ void f2b_kernel(const float* __restrict__ in, __hip_bfloat16* __restrict__ o, int n4) {
    int i = blockIdx.x * blockDim.x + threadIdx.x;
    if (i < n4) {
        floatx4 v = *(const floatx4*)(in + (size_t)i * 4);
        ushortx4 r;
        r.x = f2bu(v.x); r.y = f2bu(v.y); r.z = f2bu(v.z); r.w = f2bu(v.w);
        *(ushortx4*)((unsigned short*)o + (size_t)i * 4) = r;
    }
}

// Output-indexed transpose: Wt[n][k] = bf16(W[k][n]); W is K x Nc row-major, K = 1<<kshift.
// Coalesced bf16 writes; scattered f32 reads are L2-resident (W <= 1 MB).
__global__ void transb_kernel(const float* __restrict__ W, __hip_bfloat16* __restrict__ Wt,
                              int kshift, int Nc, int total) {
    int i = blockIdx.x * blockDim.x + threadIdx.x;
    if (i < total) {
        int K = 1 << kshift;
        int n2 = i >> kshift, k = i & (K - 1);
        Wt[i] = __float2bfloat16(W[(size_t)k * Nc + n2]);
    }
}

// ---------------- bf16 MFMA GEMM ----------------
// C[M,N] = A[M,K] @ Bt[N,K]^T (+bias).
// 2-phase double-buffered pipeline (T3-min): stage next K-tile BEFORE computing current,
// single barrier per K-step. XCD-chunked bijective block swizzle (T1/m204) so the
// n-blocks sharing an A-panel land on the same XCD L2.

template<bool STORE_BF16>
__global__ __launch_bounds__(256) void gemm_mfma(const __hip_bfloat16* __restrict__ A,
                                                 const __hip_bfloat16* __restrict__ Bt,
                                                 const float* __restrict__ bias,
                                                 float* __restrict__ Cf,
                                                 __hip_bfloat16* __restrict__ Cb,
                                                 int M, int N, int K) {
    __shared__ short As[8192];   // 2 x (128 rows x 32 k) bf16, swizzled 16B chunks
    __shared__ short Bs[8192];
    int t = threadIdx.x;
    int lane = t & 63;
    int w = t >> 6;

    // ---- XCD-chunked bijective swizzle (nwg need not be %8) ----
    int nwg = gridDim.x * gridDim.y;
    int orig = blockIdx.y * gridDim.x + blockIdx.x;
    int q = nwg >> 3, r = nwg & 7;
    int xcd = orig & 7, off = orig >> 3;
    int wgid = (xcd < r ? xcd * (q + 1) : r * (q + 1) + (xcd - r) * q) + off;
    int bx = wgid % gridDim.x;
    int by = wgid / gridDim.x;

    int m0 = by * 128;
    int n0 = bx * 128;
    int wm = (w >> 1) * 64, wn = (w & 1) * 64;

    int c0 = t, c1 = t + 256;
    int row0 = c0 >> 2, row1 = c1 >> 2;
    int kg0 = (c0 & 3) ^ ((row0 >> 1) & 3);
    int kg1 = (c1 & 3) ^ ((row1 >> 1) & 3);
    int am0 = m0 + row0; if (am0 > M - 1) am0 = M - 1;
    int am1 = m0 + row1; if (am1 > M - 1) am1 = M - 1;
    const __hip_bfloat16* Ag0 = A + (size_t)am0 * K + kg0 * 8;
    const __hip_bfloat16* Ag1 = A + (size_t)am1 * K + kg1 * 8;
    const __hip_bfloat16* Bg0 = Bt + (size_t)(n0 + row0) * K + kg0 * 8;
    const __hip_bfloat16* Bg1 = Bt + (size_t)(n0 + row1) * K + kg1 * 8;
    short* lA0 = &As[(t & 192) * 8];
    short* lA1 = &As[(256 + (t & 192)) * 8];
    short* lB0 = &Bs[(t & 192) * 8];
    short* lB1 = &Bs[(256 + (t & 192)) * 8];

    floatx4 acc[4][4];
#pragma unroll
    for (int i = 0; i < 4; i++)
#pragma unroll
        for (int j = 0; j < 4; j++) acc[i][j] = (floatx4){0.f, 0.f, 0.f, 0.f};

    int quad = lane >> 4;
    int lm = lane & 15;

    int nt = K >> 5;
    // prologue: stage tile 0 into buffer 0
    ASYNC16(Ag0, lA0);
    ASYNC16(Ag1, lA1);
    ASYNC16(Bg0, lB0);
    ASYNC16(Bg1, lB1);
    __syncthreads();   // vmcnt(0) drain + barrier: buf0 resident

    for (int tt = 0; tt < nt; ++tt) {
        int cb = (tt & 1) << 12;       // current buffer offset (shorts)
        int nb = cb ^ 4096;            // next buffer offset
        if (tt + 1 < nt) {
            int k0 = (tt + 1) << 5;
            ASYNC16(Ag0 + k0, lA0 + nb);
            ASYNC16(Ag1 + k0, lA1 + nb);
            ASYNC16(Bg0 + k0, lB0 + nb);
            ASYNC16(Bg1 + k0, lB1 + nb);
        }

        short8 af[4], bf[4];
#pragma unroll
        for (int i = 0; i < 4; i++) {
            int rm = wm + i * 16 + lm;
            af[i] = *(const short8*)&As[cb + (rm * 4 + (quad ^ ((rm >> 1) & 3))) * 8];
            int rn = wn + i * 16 + lm;
            bf[i] = *(const short8*)&Bs[cb + (rn * 4 + (quad ^ ((rn >> 1) & 3))) * 8];
        }
#pragma unroll
        for (int i = 0; i < 4; i++)
#pragma unroll
            for (int j = 0; j < 4; j++)
                acc[i][j] = __builtin_amdgcn_mfma_f32_16x16x32_bf16(af[i], bf[j], acc[i][j], 0, 0, 0);
        // single drain+barrier per K-step: the prefetch issued above had the whole
        // ds_read+MFMA phase to complete before this waits on it.
        __syncthreads();
    }

    int lr = (lane >> 4) * 4;
#pragma unroll
    for (int i = 0; i < 4; i++) {
#pragma unroll
        for (int j = 0; j < 4; j++) {
            int col = n0 + wn + j * 16 + lm;
            float bv = bias ? bias[col] : 0.0f;
#pragma unroll
            for (int r2 = 0; r2 < 4; r2++) {
                int row = m0 + wm + i * 16 + lr + r2;
                if (row < M) {
                    float v = acc[i][j][r2] + bv;
                    if (STORE_BF16) Cb[(size_t)row * N + col] = __float2bfloat16(v);
                    else            Cf[(size_t)row * N + col] = v;
                }
            }
        }
    }
}

// ---------------- el/er for all 3 etypes ----------------

__global__ __launch_bounds__(256) void elr3_kernel(const __hip_bfloat16* __restrict__ f,
                                                   const float* __restrict__ al0, const float* __restrict__ al1,
                                                   const float* __restrict__ al2, const float* __restrict__ ar0,
                                                   const float* __restrict__ ar1, const float* __restrict__ ar2,
                                                   float* __restrict__ el, float* __restrict__ er) {
    int n = blockIdx.x;
    int h = threadIdx.x >> 6;
    int d = threadIdx.x & 63;
#pragma unroll
    for (int t = 0; t < 3; t++) {
        const float* al = t == 0 ? al0 : (t == 1 ? al1 : al2);
        const float* ar = t == 0 ? ar0 : (t == 1 ? ar1 : ar2);
        float v = __bfloat162float(f[(size_t)n * 768 + t * 256 + h * DD + d]);
        float vl = v * al[h * DD + d];
        float vr = v * ar[h * DD + d];
#pragma unroll
        for (int off = 32; off; off >>= 1) {
            vl += __shfl_down(vl, off);
            vr += __shfl_down(vr, off);
        }
        if (d == 0) {
            el[n * 12 + t * 4 + h] = vl;
            er[n * 12 + t * 4 + h] = vr;
        }
    }
}

// ---------------- edge-parallel attention weights ----------------
// ex = exp(leaky(el[src]+er[dst], 0.2)). No max-subtraction: softmax is invariant to it
// and logits are O(1) here (no overflow). attn layout: [t*EE + p][h] floats.

__global__ __launch_bounds__(256) void attn3_kernel(const int* __restrict__ colsrc_all,
                                                    const int* __restrict__ coldst_all,
                                                    const float* __restrict__ el,
                                                    const float* __restrict__ er,
                                                    float* __restrict__ attn_all) {
    int p = blockIdx.x * blockDim.x + threadIdx.x;
    int t = blockIdx.y;
    if (p >= EE) return;
    int src = colsrc_all[t * EE + p];
    int dst = coldst_all[t * EE + p];
    floatx4 l = *(const floatx4*)(el + (size_t)src * 12 + t * 4);
    floatx4 r = *(const floatx4*)(er + (size_t)dst * 12 + t * 4);
    floatx4 o;
#pragma unroll
    for (int j = 0; j < 4; j++) {
        float e = l[j] + r[j];
        e = (e > 0.f) ? e : 0.2f * e;
        o[j] = __expf(e);
    }
    *(floatx4*)(attn_all + ((size_t)t * EE + p) * 4) = o;
}

// ---------------- shuffle-free aggregation ----------------
// One wave per node. Lane owns channels [lane*4, lane*4+3] (head = lane>>4).
// Per edge: uniform colsrc load + per-lane attn load + one ushort4 gather + 4 fma.
// s (softmax denom) accumulates uniformly within each 16-lane head group.

__global__ __launch_bounds__(256) void aggregate3v2_kernel(const int* __restrict__ rowptr_all,
                                                           const int* __restrict__ colsrc_all,
                                                           const float* __restrict__ attn_all,
                                                           const __hip_bfloat16* __restrict__ f,
                                                           const float* __restrict__ b0,
                                                           const float* __restrict__ b1,
                                                           const float* __restrict__ b2,
                                                           float slope,
                                                           __hip_bfloat16* __restrict__ outb) {
    int wid = threadIdx.x >> 6;
    int lane = threadIdx.x & 63;
    int n = blockIdx.x * 4 + wid;
    int hh = lane >> 4;
    const unsigned short* fbase = (const unsigned short*)f;

    float t0 = 0.f, t1 = 0.f, t2 = 0.f, t3 = 0.f;
#pragma unroll
    for (int t = 0; t < 3; t++) {
        const int* rowptr = rowptr_all + t * (NN + 1);
        const int* colsrc = colsrc_all + t * EE;
        const float* attn = attn_all + (size_t)t * EE * 4;
        const unsigned short* fb = fbase + t * 256 + lane * 4;
        int beg = rowptr[n], end = rowptr[n + 1];
        float s = 0.f, a0 = 0.f, a1 = 0.f, a2 = 0.f, a3 = 0.f;
        int p = beg;
        for (; p + 4 <= end; p += 4) {
            int i0 = colsrc[p], i1 = colsrc[p + 1], i2 = colsrc[p + 2], i3 = colsrc[p + 3];
            float e0 = attn[p * 4 + hh];
            float e1 = attn[p * 4 + 4 + hh];
            float e2 = attn[p * 4 + 8 + hh];
            float e3 = attn[p * 4 + 12 + hh];
            ushortx4 v0 = *(const ushortx4*)(fb + (size_t)i0 * 768);
            ushortx4 v1 = *(const ushortx4*)(fb + (size_t)i1 * 768);
            ushortx4 v2 = *(const ushortx4*)(fb + (size_t)i2 * 768);
            ushortx4 v3 = *(const ushortx4*)(fb + (size_t)i3 * 768);
            s += (e0 + e1) + (e2 + e3);
            a0 = fmaf(e0, b2f(v0.x), a0); a1 = fmaf(e0, b2f(v0.y), a1);
            a2 = fmaf(e0, b2f(v0.z), a2); a3 = fmaf(e0, b2f(v0.w), a3);
            a0 = fmaf(e1, b2f(v1.x), a0); a1 = fmaf(e1, b2f(v1.y), a1);
            a2 = fmaf(e1, b2f(v1.z), a2); a3 = fmaf(e1, b2f(v1.w), a3);
            a0 = fmaf(e2, b2f(v2.x), a0); a1 = fmaf(e2, b2f(v2.y), a1);
            a2 = fmaf(e2, b2f(v2.z), a2); a3 = fmaf(e2, b2f(v2.w), a3);
            a0 = fmaf(e3, b2f(v3.x), a0); a1 = fmaf(e3, b2f(v3.y), a1);
            a2 = fmaf(e3, b2f(v3.z), a2); a3 = fmaf(e3, b2f(v3.w), a3);
        }
        for (; p < end; p++) {
            int i0 = colsrc[p];
            float e0 = attn[p * 4 + hh];
            ushortx4 v0 = *(const ushortx4*)(fb + (size_t)i0 * 768);
            s += e0;
            a0 = fmaf(e0, b2f(v0.x), a0); a1 = fmaf(e0, b2f(v0.y), a1);
            a2 = fmaf(e0, b2f(v0.z), a2); a3 = fmaf(e0, b2f(v0.w), a3);
        }
        const float* bias = t == 0 ? b0 : (t == 1 ? b1 : b2);
        floatx4 bv = *(const floatx4*)(bias + lane * 4);
        if (s > 0.f) {
            float inv = 1.0f / s;
            t0 += a0 * inv; t1 += a1 * inv; t2 += a2 * inv; t3 += a3 * inv;
        }
        t0 += bv.x; t1 += bv.y; t2 += bv.z; t3 += bv.w;
    }
    t0 = (t0 >= 0.f) ? t0 : slope * t0;
    t1 = (t1 >= 0.f) ? t1 : slope * t1;
    t2 = (t2 >= 0.f) ? t2 : slope * t2;
    t3 = (t3 >= 0.f) ? t3 : slope * t3;
    ushortx4 o;
    o.x = f2bu(t0); o.y = f2bu(t1); o.z = f2bu(t2); o.w = f2bu(t3);
    *(ushortx4*)((unsigned short*)outb + (size_t)n * HDIM + lane * 4) = o;
}

// ---------------- launch ----------------

extern "C" void kernel_launch(void* const* d_in, const int* in_sizes, int n_in,
                              void* d_out, int out_size, void* d_ws, size_t ws_size,
                              hipStream_t stream) {
    const float* x = (const float*)d_in[0];
    const int* src[3] = {(const int*)d_in[1], (const int*)d_in[3], (const int*)d_in[5]};
    const int* dst[3] = {(const int*)d_in[2], (const int*)d_in[4], (const int*)d_in[6]};
    const float *W[2][3], *AL[2][3], *AR[2][3], *BB[2][3];
    int idx = 7;
    for (int l = 0; l < 2; l++)
        for (int t = 0; t < 3; t++) {
            W[l][t]  = (const float*)d_in[idx++];
            AL[l][t] = (const float*)d_in[idx++];
            AR[l][t] = (const float*)d_in[idx++];
            BB[l][t] = (const float*)d_in[idx++];
        }
    const float* Wout = (const float*)d_in[31];
    const float* bout = (const float*)d_in[32];
    float* out = (float*)d_out;

    // ---- workspace carve ----
    char* p = (char*)d_ws;
    __hip_bfloat16* f_all = (__hip_bfloat16*)p; p += (size_t)NN * 768 * 2;   // 61.44 MB
    char* regionA = p;                          p += (size_t)NN * 1024 * 2;  // 81.92 MB (xb, then hb+attn)
    float* el_all = (float*)p;                  p += (size_t)NN * 12 * 4;
    float* er_all = (float*)p;                  p += (size_t)NN * 12 * 4;
    __hip_bfloat16* Wt0 = (__hip_bfloat16*)p;   p += (size_t)768 * 1024 * 2;
    __hip_bfloat16* Wt1 = (__hip_bfloat16*)p;   p += (size_t)768 * 256 * 2;
    __hip_bfloat16* Wto = (__hip_bfloat16*)p;   p += (size_t)1024 * 256 * 2;
    int* rowptr_all = (int*)p;                  p += (size_t)3 * (NN + 1) * 4;
    int* colsrc_all = (int*)p;                  p += (size_t)3 * EE * 4;
    int* coldst_all = (int*)p;                  p += (size_t)3 * EE * 4;
    int* cursor_all = (int*)p;                  p += (size_t)3 * NN * 4;
    // regionA lifetimes:
    //   xb (layer-k GEMM input) dead once GEMM reads it;
    //   hb = regionA[0 .. 20.48 MB);  attn = regionA[32 MB .. 44 MB) — written after the
    //   GEMM consumed xb, read only by the following aggregate. No overlap with hb.
    __hip_bfloat16* xb = (__hip_bfloat16*)regionA;
    __hip_bfloat16* hb = (__hip_bfloat16*)regionA;
    float* attn_all = (float*)(regionA + (size_t)32 * 1024 * 1024);

    // ---- CSR build ----
    zero_kernel<<<(3 * NN + 255) / 256, 256, 0, stream>>>(cursor_all, 3 * NN);
    count3_kernel<<<dim3((EE + 255) / 256, 3), 256, 0, stream>>>(dst[0], dst[1], dst[2], cursor_all, EE);
    scan3_kernel<<<3, 1024, 0, stream>>>(cursor_all, rowptr_all, NN);
    zero_kernel<<<(3 * NN + 255) / 256, 256, 0, stream>>>(cursor_all, 3 * NN);
    scatter3_kernel<<<dim3((EE + 255) / 256, 3), 256, 0, stream>>>(src[0], src[1], src[2],
                                                                   dst[0], dst[1], dst[2],
                                                                   rowptr_all, cursor_all,
                                                                   colsrc_all, coldst_all, EE);

    // ---- pack inputs/weights to bf16 ----
    f2b_kernel<<<(NN * 1024 / 4 + 255) / 256, 256, 0, stream>>>(x, xb, NN * 1024 / 4);
    for (int t = 0; t < 3; t++) {
        transb_kernel<<<(1024 * 256 + 255) / 256, 256, 0, stream>>>(W[0][t], Wt0 + (size_t)t * 256 * 1024, 10, 256, 256 * 1024);
        transb_kernel<<<(256 * 256 + 255) / 256, 256, 0, stream>>>(W[1][t], Wt1 + (size_t)t * 256 * 256, 8, 256, 256 * 256);
    }
    transb_kernel<<<(256 * 1024 + 255) / 256, 256, 0, stream>>>(Wout, Wto, 8, 1024, 1024 * 256);

    // ---- layer 0 ----
    gemm_mfma<true><<<dim3(6, 313), 256, 0, stream>>>(xb, Wt0, nullptr, nullptr, f_all, NN, 768, 1024);
    elr3_kernel<<<NN, 256, 0, stream>>>(f_all, AL[0][0], AL[0][1], AL[0][2],
                                        AR[0][0], AR[0][1], AR[0][2], el_all, er_all);
    attn3_kernel<<<dim3((EE + 255) / 256, 3), 256, 0, stream>>>(colsrc_all, coldst_all, el_all, er_all, attn_all);
    aggregate3v2_kernel<<<NN / 4, 256, 0, stream>>>(rowptr_all, colsrc_all, attn_all, f_all,
                                                    BB[0][0], BB[0][1], BB[0][2], 0.01f, hb);

    // ---- layer 1 ----
    gemm_mfma<true><<<dim3(6, 313), 256, 0, stream>>>(hb, Wt1, nullptr, nullptr, f_all, NN, 768, 256);
    elr3_kernel<<<NN, 256, 0, stream>>>(f_all, AL[1][0], AL[1][1], AL[1][2],
                                        AR[1][0], AR[1][1], AR[1][2], el_all, er_all);
    attn3_kernel<<<dim3((EE + 255) / 256, 3), 256, 0, stream>>>(colsrc_all, coldst_all, el_all, er_all, attn_all);
    aggregate3v2_kernel<<<NN / 4, 256, 0, stream>>>(rowptr_all, colsrc_all, attn_all, f_all,
                                                    BB[1][0], BB[1][1], BB[1][2], 1.0f, hb);

    // ---- output projection ----
    gemm_mfma<false><<<dim3(8, 313), 256, 0, stream>>>(hb, Wto, bout, out, nullptr, NN, 1024, 256);
}

// Round 6
// 920.594 us; speedup vs baseline: 1.2996x; 1.0129x over previous
//
#include <hip/hip_runtime.h>
#include <hip/hip_bf16.h>
#include <math.h>

#define NN 40000
#define EE 250000
#define HH 4
#define DD 64
#define HDIM 256

typedef __attribute__((ext_vector_type(8))) short short8;
typedef __attribute__((ext_vector_type(4))) float floatx4;
typedef __attribute__((ext_vector_type(4))) unsigned short ushortx4;

#define ASYNC16(G, L) __builtin_amdgcn_global_load_lds( \
    (const __attribute__((address_space(1))) void*)(G), \
    (__attribute__((address_space(3))) void*)(L), 16, 0, 0)

__device__ __forceinline__ float b2f(unsigned short u) {
    return __uint_as_float((unsigned)u << 16);
}
__device__ __forceinline__ unsigned short f2bu(float x) {
    __hip_bfloat16 h = __float2bfloat16(x);
    return *(unsigned short*)&h;
}

// ---------------- CSR build ----------------

__global__ void zero_kernel(int* p, int n) {
    int i = blockIdx.x * blockDim.x + threadIdx.x;
    if (i < n) p[i] = 0;
}

// grid.y = etype
__global__ void count3_kernel(const int* __restrict__ d0, const int* __restrict__ d1,
                              const int* __restrict__ d2, int* __restrict__ deg_all, int n) {
    int i = blockIdx.x * blockDim.x + threadIdx.x;
    int t = blockIdx.y;
    const int* dst = t == 0 ? d0 : (t == 1 ? d1 : d2);
    if (i < n) atomicAdd(&deg_all[t * NN + dst[i]], 1);
}

// register-blocked scan: 1024 threads x 40 elems, wave-scan + cross-wave scan.
#define SCAN_PER 40
__global__ __launch_bounds__(1024) void scan3_kernel(const int* __restrict__ deg_all,
                                                     int* __restrict__ rowptr_all, int n) {
    const int* deg = deg_all + blockIdx.x * NN;
    int* rowptr = rowptr_all + blockIdx.x * (NN + 1);
    int tid = threadIdx.x;
    int lane = tid & 63, wv = tid >> 6;
    __shared__ int wsum[16];

    int beg = tid * SCAN_PER;
    int vals[SCAN_PER];
    int loc = 0;
#pragma unroll
    for (int j = 0; j < SCAN_PER; j++) {
        int i = beg + j;
        int v = (i < n) ? deg[i] : 0;
        vals[j] = v;
        loc += v;
    }
    // inclusive wave scan of loc
    int sc = loc;
#pragma unroll
    for (int off = 1; off < 64; off <<= 1) {
        int t2 = __shfl_up(sc, off);
        if (lane >= off) sc += t2;
    }
    if (lane == 63) wsum[wv] = sc;
    __syncthreads();
    if (wv == 0) {
        int w = (lane < 16) ? wsum[lane] : 0;
#pragma unroll
        for (int off = 1; off < 16; off <<= 1) {
            int t2 = __shfl_up(w, off);
            if (lane >= off) w += t2;
        }
        if (lane < 16) wsum[lane] = w;  // inclusive over waves
    }
    __syncthreads();
    int base = (wv > 0 ? wsum[wv - 1] : 0) + (sc - loc);  // exclusive prefix for this thread
    int run = base;
#pragma unroll
    for (int j = 0; j < SCAN_PER; j++) {
        int i = beg + j;
        run += vals[j];
        if (i < n) rowptr[i + 1] = run;
    }
    if (tid == 0) rowptr[0] = 0;
}

__global__ void scatter3_kernel(const int* __restrict__ s0, const int* __restrict__ s1,
                                const int* __restrict__ s2, const int* __restrict__ d0,
                                const int* __restrict__ d1, const int* __restrict__ d2,
                                const int* __restrict__ rowptr_all, int* __restrict__ cur_all,
                                int* __restrict__ colsrc_all, int* __restrict__ coldst_all, int n) {
    int i = blockIdx.x * blockDim.x + threadIdx.x;
    int t = blockIdx.y;
    const int* src = t == 0 ? s0 : (t == 1 ? s1 : s2);
    const int* dst = t == 0 ? d0 : (t == 1 ? d1 : d2);
    if (i < n) {
        int d = dst[i];
        int p = rowptr_all[t * (NN + 1) + d] + atomicAdd(&cur_all[t * NN + d], 1);
        colsrc_all[t * EE + p] = src[i];
        coldst_all[t * EE + p] = d;
    }
}

// ---------------- conversions / weight packing ----------------

// n4 = count of float4 groups
__global__ void f2b_kernel(const float* __restrict__ in, __hip_bfloat16* __restrict__ o, int n4) {
    int i = blockIdx.x * blockDim.x + threadIdx.x;
    if (i < n4) {
        floatx4 v = *(const floatx4*)(in + (size_t)i * 4);
        ushortx4 r;
        r.x = f2bu(v.x); r.y = f2bu(v.y); r.z = f2bu(v.z); r.w = f2bu(v.w);
        *(ushortx4*)((unsigned short*)o + (size_t)i * 4) = r;
    }
}

// Output-indexed transpose: Wt[n][k] = bf16(W[k][n]); W is K x Nc row-major, K = 1<<kshift.
// Coalesced bf16 writes; scattered f32 reads are L2-resident (W <= 1 MB).
__global__ void transb_kernel(const float* __restrict__ W, __hip_bfloat16* __restrict__ Wt,
                              int kshift, int Nc, int total) {
    int i = blockIdx.x * blockDim.x + threadIdx.x;
    if (i < total) {
        int K = 1 << kshift;
        int n2 = i >> kshift, k = i & (K - 1);
        Wt[i] = __float2bfloat16(W[(size_t)k * Nc + n2]);
    }
}

// ---------------- bf16 MFMA GEMM ----------------
// C[M,N] = A[M,K] @ Bt[N,K]^T (+bias).
// Depth-2 prefetch pipeline (T3+T4): 3-buffer LDS ring, counted s_waitcnt vmcnt(4)
// before a raw s_barrier (never drain to 0 in the main loop). Each wave waits its own
// tile-tt loads BEFORE the barrier, so after the barrier all waves' staging for the
// current buffer has landed while the next tile's 4 loads stay in flight.
// XCD-chunked bijective block swizzle (T1/m204) keeps A-panel sharers on one XCD L2.

template<bool STORE_BF16>
__global__ __launch_bounds__(256, 3) void gemm_mfma(const __hip_bfloat16* __restrict__ A,
                                                    const __hip_bfloat16* __restrict__ Bt,
                                                    const float* __restrict__ bias,
                                                    float* __restrict__ Cf,
                                                    __hip_bfloat16* __restrict__ Cb,
                                                    int M, int N, int K) {
    __shared__ short As[12288];   // 3 x (128 rows x 32 k) bf16, swizzled 16B chunks
    __shared__ short Bs[12288];
    int t = threadIdx.x;
    int lane = t & 63;
    int w = t >> 6;

    // ---- XCD-chunked bijective swizzle (nwg need not be %8) ----
    int nwg = gridDim.x * gridDim.y;
    int orig = blockIdx.y * gridDim.x + blockIdx.x;
    int q = nwg >> 3, r = nwg & 7;
    int xcd = orig & 7, off = orig >> 3;
    int wgid = (xcd < r ? xcd * (q + 1) : r * (q + 1) + (xcd - r) * q) + off;
    int bx = wgid % gridDim.x;
    int by = wgid / gridDim.x;

    int m0 = by * 128;
    int n0 = bx * 128;
    int wm = (w >> 1) * 64, wn = (w & 1) * 64;

    int c0 = t, c1 = t + 256;
    int row0 = c0 >> 2, row1 = c1 >> 2;
    int kg0 = (c0 & 3) ^ ((row0 >> 1) & 3);
    int kg1 = (c1 & 3) ^ ((row1 >> 1) & 3);
    int am0 = m0 + row0; if (am0 > M - 1) am0 = M - 1;
    int am1 = m0 + row1; if (am1 > M - 1) am1 = M - 1;
    const __hip_bfloat16* Ag0 = A + (size_t)am0 * K + kg0 * 8;
    const __hip_bfloat16* Ag1 = A + (size_t)am1 * K + kg1 * 8;
    const __hip_bfloat16* Bg0 = Bt + (size_t)(n0 + row0) * K + kg0 * 8;
    const __hip_bfloat16* Bg1 = Bt + (size_t)(n0 + row1) * K + kg1 * 8;
    short* lA0 = &As[(t & 192) * 8];
    short* lA1 = &As[(256 + (t & 192)) * 8];
    short* lB0 = &Bs[(t & 192) * 8];
    short* lB1 = &Bs[(256 + (t & 192)) * 8];

    floatx4 acc[4][4];
#pragma unroll
    for (int i = 0; i < 4; i++)
#pragma unroll
        for (int j = 0; j < 4; j++) acc[i][j] = (floatx4){0.f, 0.f, 0.f, 0.f};

    int quad = lane >> 4;
    int lm = lane & 15;

    int nt = K >> 5;   // always >= 2 here (K = 256 or 1024)
    // prologue: stage tiles 0 and 1 into ring slots 0 and 1 (8 loads in flight)
    ASYNC16(Ag0, lA0);
    ASYNC16(Ag1, lA1);
    ASYNC16(Bg0, lB0);
    ASYNC16(Bg1, lB1);
    ASYNC16(Ag0 + 32, lA0 + 4096);
    ASYNC16(Ag1 + 32, lA1 + 4096);
    ASYNC16(Bg0 + 32, lB0 + 4096);
    ASYNC16(Bg1 + 32, lB1 + 4096);

    int cb = 0;      // current ring slot (short offset)
    int sb = 8192;   // stage target slot for tile tt+2

    for (int tt = 0; tt < nt; ++tt) {
        // own tile-tt loads landed; tile-(tt+1) loads stay in flight
        if (tt < nt - 1) asm volatile("s_waitcnt vmcnt(4)" ::: "memory");
        else             asm volatile("s_waitcnt vmcnt(0)" ::: "memory");
        __builtin_amdgcn_s_barrier();
        __builtin_amdgcn_sched_barrier(0);   // pin: no ds_read/stage hoists above barrier

        short8 af[4], bf[4];
#pragma unroll
        for (int i = 0; i < 4; i++) {
            int rm = wm + i * 16 + lm;
            af[i] = *(const short8*)&As[cb + (rm * 4 + (quad ^ ((rm >> 1) & 3))) * 8];
            int rn = wn + i * 16 + lm;
            bf[i] = *(const short8*)&Bs[cb + (rn * 4 + (quad ^ ((rn >> 1) & 3))) * 8];
        }

        if (tt + 2 < nt) {
            int k0 = (tt + 2) << 5;
            ASYNC16(Ag0 + k0, lA0 + sb);
            ASYNC16(Ag1 + k0, lA1 + sb);
            ASYNC16(Bg0 + k0, lB0 + sb);
            ASYNC16(Bg1 + k0, lB1 + sb);
        }

#pragma unroll
        for (int i = 0; i < 4; i++)
#pragma unroll
            for (int j = 0; j < 4; j++)
                acc[i][j] = __builtin_amdgcn_mfma_f32_16x16x32_bf16(af[i], bf[j], acc[i][j], 0, 0, 0);

        cb += 4096; if (cb == 12288) cb = 0;
        sb += 4096; if (sb == 12288) sb = 0;
    }

    int lr = (lane >> 4) * 4;
#pragma unroll
    for (int i = 0; i < 4; i++) {
#pragma unroll
        for (int j = 0; j < 4; j++) {
            int col = n0 + wn + j * 16 + lm;
            float bv = bias ? bias[col] : 0.0f;
#pragma unroll
            for (int r2 = 0; r2 < 4; r2++) {
                int row = m0 + wm + i * 16 + lr + r2;
                if (row < M) {
                    float v = acc[i][j][r2] + bv;
                    if (STORE_BF16) Cb[(size_t)row * N + col] = __float2bfloat16(v);
                    else            Cf[(size_t)row * N + col] = v;
                }
            }
        }
    }
}

// ---------------- el/er for all 3 etypes ----------------

__global__ __launch_bounds__(256) void elr3_kernel(const __hip_bfloat16* __restrict__ f,
                                                   const float* __restrict__ al0, const float* __restrict__ al1,
                                                   const float* __restrict__ al2, const float* __restrict__ ar0,
                                                   const float* __restrict__ ar1, const float* __restrict__ ar2,
                                                   float* __restrict__ el, float* __restrict__ er) {
    int n = blockIdx.x;
    int h = threadIdx.x >> 6;
    int d = threadIdx.x & 63;
#pragma unroll
    for (int t = 0; t < 3; t++) {
        const float* al = t == 0 ? al0 : (t == 1 ? al1 : al2);
        const float* ar = t == 0 ? ar0 : (t == 1 ? ar1 : ar2);
        float v = __bfloat162float(f[(size_t)n * 768 + t * 256 + h * DD + d]);
        float vl = v * al[h * DD + d];
        float vr = v * ar[h * DD + d];
#pragma unroll
        for (int off = 32; off; off >>= 1) {
            vl += __shfl_down(vl, off);
            vr += __shfl_down(vr, off);
        }
        if (d == 0) {
            el[n * 12 + t * 4 + h] = vl;
            er[n * 12 + t * 4 + h] = vr;
        }
    }
}

// ---------------- edge-parallel attention weights ----------------
// ex = exp(leaky(el[src]+er[dst], 0.2)). No max-subtraction: softmax is invariant to it
// and logits are O(1) here (no overflow). attn layout: [t*EE + p][h] floats.

__global__ __launch_bounds__(256) void attn3_kernel(const int* __restrict__ colsrc_all,
                                                    const int* __restrict__ coldst_all,
                                                    const float* __restrict__ el,
                                                    const float* __restrict__ er,
                                                    float* __restrict__ attn_all) {
    int p = blockIdx.x * blockDim.x + threadIdx.x;
    int t = blockIdx.y;
    if (p >= EE) return;
    int src = colsrc_all[t * EE + p];
    int dst = coldst_all[t * EE + p];
    floatx4 l = *(const floatx4*)(el + (size_t)src * 12 + t * 4);
    floatx4 r = *(const floatx4*)(er + (size_t)dst * 12 + t * 4);
    floatx4 o;
#pragma unroll
    for (int j = 0; j < 4; j++) {
        float e = l[j] + r[j];
        e = (e > 0.f) ? e : 0.2f * e;
        o[j] = __expf(e);
    }
    *(floatx4*)(attn_all + ((size_t)t * EE + p) * 4) = o;
}

// ---------------- shuffle-free aggregation ----------------
// One wave per node. Lane owns channels [lane*4, lane*4+3] (head = lane>>4).
// Per edge: uniform colsrc load + per-lane attn load + one ushort4 gather + 4 fma.
// s (softmax denom) accumulates uniformly within each 16-lane head group.

__global__ __launch_bounds__(256) void aggregate3v2_kernel(const int* __restrict__ rowptr_all,
                                                           const int* __restrict__ colsrc_all,
                                                           const float* __restrict__ attn_all,
                                                           const __hip_bfloat16* __restrict__ f,
                                                           const float* __restrict__ b0,
                                                           const float* __restrict__ b1,
                                                           const float* __restrict__ b2,
                                                           float slope,
                                                           __hip_bfloat16* __restrict__ outb) {
    int wid = threadIdx.x >> 6;
    int lane = threadIdx.x & 63;
    int n = blockIdx.x * 4 + wid;
    int hh = lane >> 4;
    const unsigned short* fbase = (const unsigned short*)f;

    float t0 = 0.f, t1 = 0.f, t2 = 0.f, t3 = 0.f;
#pragma unroll
    for (int t = 0; t < 3; t++) {
        const int* rowptr = rowptr_all + t * (NN + 1);
        const int* colsrc = colsrc_all + t * EE;
        const float* attn = attn_all + (size_t)t * EE * 4;
        const unsigned short* fb = fbase + t * 256 + lane * 4;
        int beg = rowptr[n], end = rowptr[n + 1];
        float s = 0.f, a0 = 0.f, a1 = 0.f, a2 = 0.f, a3 = 0.f;
        int p = beg;
        for (; p + 4 <= end; p += 4) {
            int i0 = colsrc[p], i1 = colsrc[p + 1], i2 = colsrc[p + 2], i3 = colsrc[p + 3];
            float e0 = attn[p * 4 + hh];
            float e1 = attn[p * 4 + 4 + hh];
            float e2 = attn[p * 4 + 8 + hh];
            float e3 = attn[p * 4 + 12 + hh];
            ushortx4 v0 = *(const ushortx4*)(fb + (size_t)i0 * 768);
            ushortx4 v1 = *(const ushortx4*)(fb + (size_t)i1 * 768);
            ushortx4 v2 = *(const ushortx4*)(fb + (size_t)i2 * 768);
            ushortx4 v3 = *(const ushortx4*)(fb + (size_t)i3 * 768);
            s += (e0 + e1) + (e2 + e3);
            a0 = fmaf(e0, b2f(v0.x), a0); a1 = fmaf(e0, b2f(v0.y), a1);
            a2 = fmaf(e0, b2f(v0.z), a2); a3 = fmaf(e0, b2f(v0.w), a3);
            a0 = fmaf(e1, b2f(v1.x), a0); a1 = fmaf(e1, b2f(v1.y), a1);
            a2 = fmaf(e1, b2f(v1.z), a2); a3 = fmaf(e1, b2f(v1.w), a3);
            a0 = fmaf(e2, b2f(v2.x), a0); a1 = fmaf(e2, b2f(v2.y), a1);
            a2 = fmaf(e2, b2f(v2.z), a2); a3 = fmaf(e2, b2f(v2.w), a3);
            a0 = fmaf(e3, b2f(v3.x), a0); a1 = fmaf(e3, b2f(v3.y), a1);
            a2 = fmaf(e3, b2f(v3.z), a2); a3 = fmaf(e3, b2f(v3.w), a3);
        }
        for (; p < end; p++) {
            int i0 = colsrc[p];
            float e0 = attn[p * 4 + hh];
            ushortx4 v0 = *(const ushortx4*)(fb + (size_t)i0 * 768);
            s += e0;
            a0 = fmaf(e0, b2f(v0.x), a0); a1 = fmaf(e0, b2f(v0.y), a1);
            a2 = fmaf(e0, b2f(v0.z), a2); a3 = fmaf(e0, b2f(v0.w), a3);
        }
        const float* bias = t == 0 ? b0 : (t == 1 ? b1 : b2);
        floatx4 bv = *(const floatx4*)(bias + lane * 4);
        if (s > 0.f) {
            float inv = 1.0f / s;
            t0 += a0 * inv; t1 += a1 * inv; t2 += a2 * inv; t3 += a3 * inv;
        }
        t0 += bv.x; t1 += bv.y; t2 += bv.z; t3 += bv.w;
    }
    t0 = (t0 >= 0.f) ? t0 : slope * t0;
    t1 = (t1 >= 0.f) ? t1 : slope * t1;
    t2 = (t2 >= 0.f) ? t2 : slope * t2;
    t3 = (t3 >= 0.f) ? t3 : slope * t3;
    ushortx4 o;
    o.x = f2bu(t0); o.y = f2bu(t1); o.z = f2bu(t2); o.w = f2bu(t3);
    *(ushortx4*)((unsigned short*)outb + (size_t)n * HDIM + lane * 4) = o;
}

// ---------------- launch ----------------

extern "C" void kernel_launch(void* const* d_in, const int* in_sizes, int n_in,
                              void* d_out, int out_size, void* d_ws, size_t ws_size,
                              hipStream_t stream) {
    const float* x = (const float*)d_in[0];
    const int* src[3] = {(const int*)d_in[1], (const int*)d_in[3], (const int*)d_in[5]};
    const int* dst[3] = {(const int*)d_in[2], (const int*)d_in[4], (const int*)d_in[6]};
    const float *W[2][3], *AL[2][3], *AR[2][3], *BB[2][3];
    int idx = 7;
    for (int l = 0; l < 2; l++)
        for (int t = 0; t < 3; t++) {
            W[l][t]  = (const float*)d_in[idx++];
            AL[l][t] = (const float*)d_in[idx++];
            AR[l][t] = (const float*)d_in[idx++];
            BB[l][t] = (const float*)d_in[idx++];
        }
    const float* Wout = (const float*)d_in[31];
    const float* bout = (const float*)d_in[32];
    float* out = (float*)d_out;

    // ---- workspace carve ----
    char* p = (char*)d_ws;
    __hip_bfloat16* f_all = (__hip_bfloat16*)p; p += (size_t)NN * 768 * 2;   // 61.44 MB
    char* regionA = p;                          p += (size_t)NN * 1024 * 2;  // 81.92 MB (xb, then hb+attn)
    float* el_all = (float*)p;                  p += (size_t)NN * 12 * 4;
    float* er_all = (float*)p;                  p += (size_t)NN * 12 * 4;
    __hip_bfloat16* Wt0 = (__hip_bfloat16*)p;   p += (size_t)768 * 1024 * 2;
    __hip_bfloat16* Wt1 = (__hip_bfloat16*)p;   p += (size_t)768 * 256 * 2;
    __hip_bfloat16* Wto = (__hip_bfloat16*)p;   p += (size_t)1024 * 256 * 2;
    int* rowptr_all = (int*)p;                  p += (size_t)3 * (NN + 1) * 4;
    int* colsrc_all = (int*)p;                  p += (size_t)3 * EE * 4;
    int* coldst_all = (int*)p;                  p += (size_t)3 * EE * 4;
    int* cursor_all = (int*)p;                  p += (size_t)3 * NN * 4;
    // regionA lifetimes:
    //   xb (layer-k GEMM input) dead once GEMM reads it;
    //   hb = regionA[0 .. 20.48 MB);  attn = regionA[32 MB .. 44 MB) — written after the
    //   GEMM consumed xb, read only by the following aggregate. No overlap with hb.
    __hip_bfloat16* xb = (__hip_bfloat16*)regionA;
    __hip_bfloat16* hb = (__hip_bfloat16*)regionA;
    float* attn_all = (float*)(regionA + (size_t)32 * 1024 * 1024);

    // ---- CSR build ----
    zero_kernel<<<(3 * NN + 255) / 256, 256, 0, stream>>>(cursor_all, 3 * NN);
    count3_kernel<<<dim3((EE + 255) / 256, 3), 256, 0, stream>>>(dst[0], dst[1], dst[2], cursor_all, EE);
    scan3_kernel<<<3, 1024, 0, stream>>>(cursor_all, rowptr_all, NN);
    zero_kernel<<<(3 * NN + 255) / 256, 256, 0, stream>>>(cursor_all, 3 * NN);
    scatter3_kernel<<<dim3((EE + 255) / 256, 3), 256, 0, stream>>>(src[0], src[1], src[2],
                                                                   dst[0], dst[1], dst[2],
                                                                   rowptr_all, cursor_all,
                                                                   colsrc_all, coldst_all, EE);

    // ---- pack inputs/weights to bf16 ----
    f2b_kernel<<<(NN * 1024 / 4 + 255) / 256, 256, 0, stream>>>(x, xb, NN * 1024 / 4);
    for (int t = 0; t < 3; t++) {
        transb_kernel<<<(1024 * 256 + 255) / 256, 256, 0, stream>>>(W[0][t], Wt0 + (size_t)t * 256 * 1024, 10, 256, 256 * 1024);
        transb_kernel<<<(256 * 256 + 255) / 256, 256, 0, stream>>>(W[1][t], Wt1 + (size_t)t * 256 * 256, 8, 256, 256 * 256);
    }
    transb_kernel<<<(256 * 1024 + 255) / 256, 256, 0, stream>>>(Wout, Wto, 8, 1024, 1024 * 256);

    // ---- layer 0 ----
    gemm_mfma<true><<<dim3(6, 313), 256, 0, stream>>>(xb, Wt0, nullptr, nullptr, f_all, NN, 768, 1024);
    elr3_kernel<<<NN, 256, 0, stream>>>(f_all, AL[0][0], AL[0][1], AL[0][2],
                                        AR[0][0], AR[0][1], AR[0][2], el_all, er_all);
    attn3_kernel<<<dim3((EE + 255) / 256, 3), 256, 0, stream>>>(colsrc_all, coldst_all, el_all, er_all, attn_all);
    aggregate3v2_kernel<<<NN / 4, 256, 0, stream>>>(rowptr_all, colsrc_all, attn_all, f_all,
                                                    BB[0][0], BB[0][1], BB[0][2], 0.01f, hb);

    // ---- layer 1 ----
    gemm_mfma<true><<<dim3(6, 313), 256, 0, stream>>>(hb, Wt1, nullptr, nullptr, f_all, NN, 768, 256);
    elr3_kernel<<<NN, 256, 0, stream>>>(f_all, AL[1][0], AL[1][1], AL[1][2],
                                        AR[1][0], AR[1][1], AR[1][2], el_all, er_all);
    attn3_kernel<<<dim3((EE + 255) / 256, 3), 256, 0, stream>>>(colsrc_all, coldst_all, el_all, er_all, attn_all);
    aggregate3v2_kernel<<<NN / 4, 256, 0, stream>>>(rowptr_all, colsrc_all, attn_all, f_all,
                                                    BB[1][0], BB[1][1], BB[1][2], 1.0f, hb);

    // ---- output projection ----
    gemm_mfma<false><<<dim3(8, 313), 256, 0, stream>>>(hb, Wto, bout, out, nullptr, NN, 1024, 256);
}